// Round 1
// baseline (1210.047 us; speedup 1.0000x reference)
//
#include <hip/hip_runtime.h>
#include <hip/hip_bf16.h>

// CMHSA baseline (round 0): fp32 tiled GEMMs, no MFMA yet.
// B=4 C=512 T=1024 HEADS=8 HD=64. Norm deferred past PV via affine trick.
#define B_ 4
#define C_ 512
#define T_ 1024
#define HEADS_ 8
#define HD_ 64
#define SCALE_ 0.125f
#define EPS_ 1e-5f

// ws layout (floats), total exactly 16777216 floats = 64 MiB:
//   Q [B][C][T]            @ 0        (2097152)
//   K [B][C][T]            @ 2097152
//   V [B][C][T]            @ 4194304
//   S/P [8][T][T] per-batch@ 6291456  (8388608, reused for all b)
//   O [B][8][T][HD]        @ 14680064 (2097152)
// sumsq stats (32 floats) live in the tail of d_out (overwritten by proj last).
#define QOFF   0u
#define KOFF   2097152u
#define VOFF   4194304u
#define SOFF   6291456u
#define OOFF   14680064u

__device__ __forceinline__ float waveMax(float v) {
#pragma unroll
  for (int o = 32; o > 0; o >>= 1) v = fmaxf(v, __shfl_down(v, o, 64));
  return v;
}
__device__ __forceinline__ float waveSum(float v) {
#pragma unroll
  for (int o = 32; o > 0; o >>= 1) v += __shfl_down(v, o, 64);
  return v;
}

__global__ __launch_bounds__(64) void init_stats(float* __restrict__ stats) {
  if (threadIdx.x < 32) stats[threadIdx.x] = 0.f;
}

// Y[b][m][t] = sum_c W[m][c] * X[b][c][t]   for W in {wq,wk,wv}
__global__ __launch_bounds__(256) void gemm_qkv(
    const float* __restrict__ x, const float* __restrict__ wq,
    const float* __restrict__ wk, const float* __restrict__ wv,
    float* __restrict__ ws) {
  const int which = blockIdx.z >> 2;  // 0=Q 1=K 2=V
  const int b = blockIdx.z & 3;
  const float* __restrict__ W = (which == 0) ? wq : (which == 1) ? wk : wv;
  float* __restrict__ Y = ws + (size_t)which * 2097152u + (size_t)b * (C_ * T_);
  const float* __restrict__ X = x + (size_t)b * (C_ * T_);
  const int m0 = blockIdx.y << 6;
  const int n0 = blockIdx.x << 6;

  __shared__ float Ws[64][65];  // [k][m]
  __shared__ float Xs[64][65];  // [k][n]
  const int tid = threadIdx.x;
  const int ty = tid >> 4, tx = tid & 15;
  float acc[4][4] = {};

  for (int c0 = 0; c0 < C_; c0 += 64) {
#pragma unroll
    for (int i = 0; i < 16; ++i) {
      const int e = tid + (i << 8);
      const int r = e >> 6, cc = e & 63;
      Ws[cc][r] = W[(size_t)(m0 + r) * C_ + (c0 + cc)];
      Xs[r][cc] = X[(size_t)(c0 + r) * T_ + (n0 + cc)];
    }
    __syncthreads();
#pragma unroll 16
    for (int kk = 0; kk < 64; ++kk) {
      float a[4], bb[4];
#pragma unroll
      for (int i = 0; i < 4; ++i) a[i] = Ws[kk][ty * 4 + i];
#pragma unroll
      for (int j = 0; j < 4; ++j) bb[j] = Xs[kk][tx * 4 + j];
#pragma unroll
      for (int i = 0; i < 4; ++i)
#pragma unroll
        for (int j = 0; j < 4; ++j) acc[i][j] = fmaf(a[i], bb[j], acc[i][j]);
    }
    __syncthreads();
  }
#pragma unroll
  for (int i = 0; i < 4; ++i)
#pragma unroll
    for (int j = 0; j < 4; ++j)
      Y[(size_t)(m0 + ty * 4 + i) * T_ + (n0 + tx * 4 + j)] = acc[i][j];
}

// S[h][q][t] = SCALE * sum_d Q[b][h*64+d][q] * K[b][h*64+d][t]   (per batch b)
__global__ __launch_bounds__(256) void gemm_qk(float* __restrict__ ws, int b) {
  const int h = blockIdx.z;
  const float* __restrict__ Q =
      ws + QOFF + (size_t)b * (C_ * T_) + (size_t)(h * HD_) * T_;
  const float* __restrict__ K =
      ws + KOFF + (size_t)b * (C_ * T_) + (size_t)(h * HD_) * T_;
  float* __restrict__ S = ws + SOFF + (size_t)h * ((size_t)T_ * T_);
  const int q0 = blockIdx.y << 6;
  const int t0 = blockIdx.x << 6;
  __shared__ float Qs[64][65];  // [d][q]
  __shared__ float Ks[64][65];  // [d][t]
  const int tid = threadIdx.x;
  const int ty = tid >> 4, tx = tid & 15;
#pragma unroll
  for (int i = 0; i < 16; ++i) {
    const int e = tid + (i << 8);
    const int r = e >> 6, cc = e & 63;
    Qs[r][cc] = Q[(size_t)r * T_ + (q0 + cc)];
    Ks[r][cc] = K[(size_t)r * T_ + (t0 + cc)];
  }
  __syncthreads();
  float acc[4][4] = {};
#pragma unroll 16
  for (int d = 0; d < 64; ++d) {
    float a[4], bb[4];
#pragma unroll
    for (int i = 0; i < 4; ++i) a[i] = Qs[d][ty * 4 + i];
#pragma unroll
    for (int j = 0; j < 4; ++j) bb[j] = Ks[d][tx * 4 + j];
#pragma unroll
    for (int i = 0; i < 4; ++i)
#pragma unroll
      for (int j = 0; j < 4; ++j) acc[i][j] = fmaf(a[i], bb[j], acc[i][j]);
  }
#pragma unroll
  for (int i = 0; i < 4; ++i)
#pragma unroll
    for (int j = 0; j < 4; ++j)
      S[(size_t)(q0 + ty * 4 + i) * T_ + (t0 + tx * 4 + j)] =
          acc[i][j] * SCALE_;
}

// per (q): mix 8 heads -> 8 mixed rows, softmax each, write P in place,
// accumulate sum(p^2) per (b,g) into stats (d_out tail).
__global__ __launch_bounds__(256) void mix_softmax(float* __restrict__ ws,
                                                   const float* __restrict__ wh,
                                                   float* __restrict__ stats,
                                                   int b) {
  const int q = blockIdx.x;
  __shared__ float Srow[8][1024];
  __shared__ float whs[64];
  __shared__ float red[4];
  float* __restrict__ Sb = ws + SOFF + (size_t)q * T_;
  const int tid = threadIdx.x;
  if (tid < 64) whs[tid] = wh[tid];
#pragma unroll
  for (int h = 0; h < 8; ++h)
    for (int i = tid; i < 1024; i += 256)
      Srow[h][i] = Sb[(size_t)h * ((size_t)T_ * T_) + i];
  __syncthreads();

  const int lane = tid & 63, wid = tid >> 6;
#pragma unroll 1
  for (int g = 0; g < 8; ++g) {
    float v[4];
#pragma unroll
    for (int i = 0; i < 4; ++i) {
      const int t = tid + (i << 8);
      float s = 0.f;
#pragma unroll
      for (int h = 0; h < 8; ++h) s = fmaf(whs[g * 8 + h], Srow[h][t], s);
      v[i] = s;
    }
    float m = fmaxf(fmaxf(v[0], v[1]), fmaxf(v[2], v[3]));
    m = waveMax(m);
    if (lane == 0) red[wid] = m;
    __syncthreads();
    m = fmaxf(fmaxf(red[0], red[1]), fmaxf(red[2], red[3]));
    __syncthreads();
    float lsum = 0.f;
#pragma unroll
    for (int i = 0; i < 4; ++i) {
      v[i] = __expf(v[i] - m);
      lsum += v[i];
    }
    lsum = waveSum(lsum);
    if (lane == 0) red[wid] = lsum;
    __syncthreads();
    const float inv = 1.f / (red[0] + red[1] + red[2] + red[3]);
    __syncthreads();
    float lssq = 0.f;
#pragma unroll
    for (int i = 0; i < 4; ++i) {
      const int t = tid + (i << 8);
      const float p = v[i] * inv;
      lssq = fmaf(p, p, lssq);
      Sb[(size_t)g * ((size_t)T_ * T_) + t] = p;
    }
    lssq = waveSum(lssq);
    if (lane == 0) red[wid] = lssq;
    __syncthreads();
    if (tid == 0) atomicAdd(stats + (b * 8 + g), red[0] + red[1] + red[2] + red[3]);
    __syncthreads();
  }
}

// O[b][g][q][d] = al*(sum_t P[g][q][t]*V[b][g*64+d][t]) + bt*Vsum[d]
// Vsum computed on the fly from the V tiles already in LDS.
__global__ __launch_bounds__(256) void gemm_pv(float* __restrict__ ws,
                                               const float* __restrict__ gamma,
                                               const float* __restrict__ beta,
                                               const float* __restrict__ stats,
                                               int b) {
  const int g = blockIdx.y;
  const int q0 = blockIdx.x << 5;  // 32-row q tiles -> 256 blocks/batch
  const float* __restrict__ P = ws + SOFF + (size_t)g * ((size_t)T_ * T_);
  const float* __restrict__ V =
      ws + VOFF + (size_t)b * (C_ * T_) + (size_t)(g * HD_) * T_;
  float* __restrict__ O =
      ws + OOFF + (size_t)(b * HEADS_ + g) * ((size_t)T_ * HD_);
  __shared__ float Ps[64][33];  // [t][q]
  __shared__ float Vs[64][65];  // [t][d]
  const int tid = threadIdx.x;
  const int ty = tid >> 4, tx = tid & 15;
  float acc[2][4] = {};
  float vsum[4] = {};
  for (int t0 = 0; t0 < T_; t0 += 64) {
#pragma unroll
    for (int i = 0; i < 8; ++i) {
      const int e = tid + (i << 8);
      const int r = e >> 6, cc = e & 63;  // r: q 0..31, cc: t
      Ps[cc][r] = P[(size_t)(q0 + r) * T_ + (t0 + cc)];
    }
#pragma unroll
    for (int i = 0; i < 16; ++i) {
      const int e = tid + (i << 8);
      const int r = e >> 6, cc = e & 63;  // r: d, cc: t
      Vs[cc][r] = V[(size_t)r * T_ + (t0 + cc)];
    }
    __syncthreads();
#pragma unroll 16
    for (int tt = 0; tt < 64; ++tt) {
      const float a0 = Ps[tt][ty * 2 + 0];
      const float a1 = Ps[tt][ty * 2 + 1];
      float bb[4];
#pragma unroll
      for (int j = 0; j < 4; ++j) bb[j] = Vs[tt][tx * 4 + j];
#pragma unroll
      for (int j = 0; j < 4; ++j) {
        acc[0][j] = fmaf(a0, bb[j], acc[0][j]);
        acc[1][j] = fmaf(a1, bb[j], acc[1][j]);
        vsum[j] += bb[j];
      }
    }
    __syncthreads();
  }
  const float ssq = stats[b * 8 + g];
  const float mean = 0.0009765625f;  // 1/1024
  const float var = ssq * (1.f / 1048576.f) - mean * mean;
  const float istd = rsqrtf(var + EPS_);
  const float al = gamma[g] * istd;
  const float bt = beta[g] - al * mean;
#pragma unroll
  for (int i = 0; i < 2; ++i)
#pragma unroll
    for (int j = 0; j < 4; ++j)
      O[(size_t)(q0 + ty * 2 + i) * HD_ + (tx * 4 + j)] =
          al * acc[i][j] + bt * vsum[j];
}

// y[b][o][t] = sum_c M[b][t][c]*wp[o][c] + bp[o]
// M[b][t][c] = O[b][t>>7][(t&127)*8 + (c>>6)][c&63]
__global__ __launch_bounds__(256) void gemm_proj(const float* __restrict__ ws,
                                                 const float* __restrict__ wp,
                                                 const float* __restrict__ bp,
                                                 float* __restrict__ y) {
  const int b = blockIdx.z;
  const int o0 = blockIdx.y << 6;
  const int t0 = blockIdx.x << 6;
  const float* __restrict__ Ob = ws + OOFF + (size_t)b * (HEADS_ * T_ * HD_);
  __shared__ float Wt[64][65];  // [c][o]
  __shared__ float Mt[64][65];  // [c][t]
  const int tid = threadIdx.x;
  const int ty = tid >> 4, tx = tid & 15;
  float acc[4][4] = {};
  for (int c0 = 0; c0 < C_; c0 += 64) {
    const int qlo = c0 >> 6;
#pragma unroll
    for (int i = 0; i < 16; ++i) {
      const int e = tid + (i << 8);
      const int r = e >> 6, cc = e & 63;
      Wt[cc][r] = wp[(size_t)(o0 + r) * C_ + (c0 + cc)];
      const int t = t0 + r;
      Mt[cc][r] = Ob[(size_t)(t >> 7) * (T_ * HD_) +
                     (size_t)(((t & 127) << 3) + qlo) * HD_ + cc];
    }
    __syncthreads();
#pragma unroll 16
    for (int kk = 0; kk < 64; ++kk) {
      float a[4], bb[4];
#pragma unroll
      for (int i = 0; i < 4; ++i) a[i] = Wt[kk][ty * 4 + i];
#pragma unroll
      for (int j = 0; j < 4; ++j) bb[j] = Mt[kk][tx * 4 + j];
#pragma unroll
      for (int i = 0; i < 4; ++i)
#pragma unroll
        for (int j = 0; j < 4; ++j) acc[i][j] = fmaf(a[i], bb[j], acc[i][j]);
    }
    __syncthreads();
  }
#pragma unroll
  for (int i = 0; i < 4; ++i) {
    const float bias = bp[o0 + ty * 4 + i];
#pragma unroll
    for (int j = 0; j < 4; ++j)
      y[(size_t)b * (C_ * T_) + (size_t)(o0 + ty * 4 + i) * T_ +
        (t0 + tx * 4 + j)] = acc[i][j] + bias;
  }
}

extern "C" void kernel_launch(void* const* d_in, const int* in_sizes, int n_in,
                              void* d_out, int out_size, void* d_ws,
                              size_t ws_size, hipStream_t stream) {
  const float* x = (const float*)d_in[0];
  const float* wq = (const float*)d_in[1];
  const float* wk = (const float*)d_in[2];
  const float* wv = (const float*)d_in[3];
  const float* wh = (const float*)d_in[4];
  const float* gm = (const float*)d_in[5];
  const float* bt = (const float*)d_in[6];
  const float* wp = (const float*)d_in[7];
  const float* bp = (const float*)d_in[8];
  float* y = (float*)d_out;
  float* ws = (float*)d_ws;
  // sumsq stats live in the last 32 floats of d_out; proj overwrites them last.
  float* stats = y + (size_t)(B_ * C_ * T_) - 32;

  init_stats<<<dim3(1), dim3(64), 0, stream>>>(stats);
  gemm_qkv<<<dim3(16, 8, 12), dim3(256), 0, stream>>>(x, wq, wk, wv, ws);
  for (int b = 0; b < B_; ++b) {
    gemm_qk<<<dim3(16, 16, 8), dim3(256), 0, stream>>>(ws, b);
    mix_softmax<<<dim3(1024), dim3(256), 0, stream>>>(ws, wh, stats, b);
    gemm_pv<<<dim3(32, 8), dim3(256), 0, stream>>>(ws, gm, bt, stats, b);
  }
  gemm_proj<<<dim3(16, 8, 4), dim3(256), 0, stream>>>(ws, wp, bp, y);
}

// Round 2
// 303.891 us; speedup vs baseline: 3.9818x; 3.9818x over previous
//
#include <hip/hip_runtime.h>
#include <hip/hip_bf16.h>

#define B_ 4
#define C_ 512
#define T_ 1024
#define SCALE_ 0.125f
#define EPS_ 1e-5f

typedef unsigned short u16;
typedef __attribute__((ext_vector_type(8))) unsigned short u16x8;
typedef __attribute__((ext_vector_type(4))) unsigned short u16x4;
typedef __attribute__((ext_vector_type(8))) short s16x8;
typedef __attribute__((ext_vector_type(4))) float f32x4;

// ws byte offsets (total 52 MB + 40 KB)
#define QT_OFF   (0ull)            // bf16 Qt[B][T][C]  4 MB
#define KT_OFF   (4ull<<20)        // bf16 Kt[B][T][C]  4 MB
#define V_OFF    (8ull<<20)        // bf16 V [B][C][T]  4 MB
#define XT_OFF   (12ull<<20)       // bf16 Xt[B][T][C]  4 MB
#define S_OFF    (16ull<<20)       // fp32 S[8][T][T]   32 MB (P bf16 aliased in row fronts)
#define O_OFF    (48ull<<20)       // bf16 O[B][8][T][64] 4 MB
#define VSUM_OFF (52ull<<20)       // fp32 vsum[B][8][64] 8 KB
#define PSSQ_OFF ((52ull<<20) + 8192ull) // fp32 pssq[8][1024] 32 KB

static __device__ __forceinline__ u16 f2bf(float f) {
  unsigned u = __float_as_uint(f);
  unsigned r = (u + 0x7fff + ((u >> 16) & 1)) >> 16;  // RNE
  return (u16)r;
}
static __device__ __forceinline__ float b2f(u16 x) {
  return __uint_as_float(((unsigned)x) << 16);
}
static __device__ __forceinline__ f32x4 mfma16(s16x8 a, s16x8 b, f32x4 c) {
  return __builtin_amdgcn_mfma_f32_16x16x32_bf16(a, b, c, 0, 0, 0);
}

// ---------------- transpose x -> Xt[b][t][c] bf16 ----------------
__global__ __launch_bounds__(256) void transpose_x(const float* __restrict__ x,
                                                   u16* __restrict__ xt) {
  const int b = blockIdx.z;
  const int t0 = blockIdx.x << 6;
  const int c0 = blockIdx.y << 6;
  const float* __restrict__ X = x + (size_t)b * (C_ * (size_t)T_);
  u16* __restrict__ Xt = xt + (size_t)b * (T_ * (size_t)C_);
  __shared__ float Ts[64][65];
  const int tid = threadIdx.x;
#pragma unroll
  for (int i = 0; i < 4; ++i) {
    const int e = tid + (i << 8);
    const int r = e >> 4, c4 = e & 15;
    const float4 v = *(const float4*)(X + (size_t)(c0 + r) * T_ + t0 + (c4 << 2));
    Ts[r][(c4 << 2) + 0] = v.x; Ts[r][(c4 << 2) + 1] = v.y;
    Ts[r][(c4 << 2) + 2] = v.z; Ts[r][(c4 << 2) + 3] = v.w;
  }
  __syncthreads();
#pragma unroll
  for (int i = 0; i < 2; ++i) {
    const int e = tid + (i << 8);
    const int tt = e >> 3, c8 = e & 7;
    u16x8 o;
#pragma unroll
    for (int j = 0; j < 8; ++j) o[j] = f2bf(Ts[(c8 << 3) + j][tt]);
    *(u16x8*)(Xt + (size_t)(t0 + tt) * C_ + c0 + (c8 << 3)) = o;
  }
}

// ---------------- Qt/Kt = Xt @ W^T  -> [t][o] bf16 ----------------
__global__ __launch_bounds__(256) void gemm_qkt(const u16* __restrict__ xt,
                                                const float* __restrict__ wq,
                                                const float* __restrict__ wk,
                                                u16* __restrict__ qto,
                                                u16* __restrict__ kto) {
  const int which = blockIdx.z >> 2;
  const int b = blockIdx.z & 3;
  const float* __restrict__ W = which ? wk : wq;
  u16* __restrict__ Y = (which ? kto : qto) + (size_t)b * (T_ * (size_t)C_);
  const u16* __restrict__ A = xt + (size_t)b * (T_ * (size_t)C_);
  const int m0 = blockIdx.x << 7;  // t
  const int n0 = blockIdx.y << 7;  // o
  __shared__ u16 As[128][40];
  __shared__ u16 Bs[128][40];
  const int tid = threadIdx.x;
  const int w = tid >> 6, lane = tid & 63, lr = lane & 15, lq = lane >> 4;
  const int mw = (w >> 1) << 6, nw = (w & 1) << 6;
  f32x4 acc[4][4] = {};
  for (int k0 = 0; k0 < C_; k0 += 32) {
#pragma unroll
    for (int it = 0; it < 2; ++it) {
      const int e = tid + (it << 8);
      const int r = e >> 2, c4 = e & 3;
      *(u16x8*)&As[r][c4 << 3] =
          *(const u16x8*)(A + (size_t)(m0 + r) * C_ + k0 + (c4 << 3));
      const float* wr = W + (size_t)(n0 + r) * C_ + k0 + (c4 << 3);
      const float4 f0 = *(const float4*)wr;
      const float4 f1 = *(const float4*)(wr + 4);
      u16x8 o;
      o[0] = f2bf(f0.x); o[1] = f2bf(f0.y); o[2] = f2bf(f0.z); o[3] = f2bf(f0.w);
      o[4] = f2bf(f1.x); o[5] = f2bf(f1.y); o[6] = f2bf(f1.z); o[7] = f2bf(f1.w);
      *(u16x8*)&Bs[r][c4 << 3] = o;
    }
    __syncthreads();
    const int ko = lq << 3;
    s16x8 a[4], bb[4];
#pragma unroll
    for (int i = 0; i < 4; ++i) a[i] = *(const s16x8*)&As[mw + (i << 4) + lr][ko];
#pragma unroll
    for (int j = 0; j < 4; ++j) bb[j] = *(const s16x8*)&Bs[nw + (j << 4) + lr][ko];
#pragma unroll
    for (int i = 0; i < 4; ++i)
#pragma unroll
      for (int j = 0; j < 4; ++j) acc[i][j] = mfma16(a[i], bb[j], acc[i][j]);
    __syncthreads();
  }
#pragma unroll
  for (int i = 0; i < 4; ++i) {
    const int row = mw + (i << 4) + (lq << 2);
#pragma unroll
    for (int j = 0; j < 4; ++j) {
      const int col = nw + (j << 4) + lr;
#pragma unroll
      for (int r = 0; r < 4; ++r)
        Y[(size_t)(m0 + row + r) * C_ + n0 + col] = f2bf(acc[i][j][r]);
    }
  }
}

// ---------------- V = Wv @ X  -> [o][t] bf16 ----------------
__global__ __launch_bounds__(256) void gemm_v(const u16* __restrict__ xt,
                                              const float* __restrict__ wv,
                                              u16* __restrict__ vout) {
  const int b = blockIdx.z;
  const int n0 = blockIdx.x << 7;  // t
  const int m0 = blockIdx.y << 7;  // o
  const u16* __restrict__ Bg = xt + (size_t)b * (T_ * (size_t)C_);
  u16* __restrict__ Y = vout + (size_t)b * (C_ * (size_t)T_);
  __shared__ u16 As[128][40];
  __shared__ u16 Bs[128][40];
  const int tid = threadIdx.x;
  const int w = tid >> 6, lane = tid & 63, lr = lane & 15, lq = lane >> 4;
  const int mw = (w >> 1) << 6, nw = (w & 1) << 6;
  f32x4 acc[4][4] = {};
  for (int k0 = 0; k0 < C_; k0 += 32) {
#pragma unroll
    for (int it = 0; it < 2; ++it) {
      const int e = tid + (it << 8);
      const int r = e >> 2, c4 = e & 3;
      const float* wr = wv + (size_t)(m0 + r) * C_ + k0 + (c4 << 3);
      const float4 f0 = *(const float4*)wr;
      const float4 f1 = *(const float4*)(wr + 4);
      u16x8 o;
      o[0] = f2bf(f0.x); o[1] = f2bf(f0.y); o[2] = f2bf(f0.z); o[3] = f2bf(f0.w);
      o[4] = f2bf(f1.x); o[5] = f2bf(f1.y); o[6] = f2bf(f1.z); o[7] = f2bf(f1.w);
      *(u16x8*)&As[r][c4 << 3] = o;
      *(u16x8*)&Bs[r][c4 << 3] =
          *(const u16x8*)(Bg + (size_t)(n0 + r) * C_ + k0 + (c4 << 3));
    }
    __syncthreads();
    const int ko = lq << 3;
    s16x8 a[4], bb[4];
#pragma unroll
    for (int i = 0; i < 4; ++i) a[i] = *(const s16x8*)&As[mw + (i << 4) + lr][ko];
#pragma unroll
    for (int j = 0; j < 4; ++j) bb[j] = *(const s16x8*)&Bs[nw + (j << 4) + lr][ko];
#pragma unroll
    for (int i = 0; i < 4; ++i)
#pragma unroll
      for (int j = 0; j < 4; ++j) acc[i][j] = mfma16(a[i], bb[j], acc[i][j]);
    __syncthreads();
  }
#pragma unroll
  for (int i = 0; i < 4; ++i) {
    const int row = mw + (i << 4) + (lq << 2);
#pragma unroll
    for (int j = 0; j < 4; ++j) {
      const int col = nw + (j << 4) + lr;
#pragma unroll
      for (int r = 0; r < 4; ++r)
        Y[(size_t)(m0 + row + r) * T_ + n0 + col] = f2bf(acc[i][j][r]);
    }
  }
}

// ---------------- vsum[b][g][d] = sum_t V ----------------
__global__ __launch_bounds__(256) void vsum_k(const u16* __restrict__ v,
                                              float* __restrict__ vsum) {
  const int bg = blockIdx.x;  // b*8+g
  const int tid = threadIdx.x;
  const int d = tid >> 2, part = tid & 3;
  const u16* __restrict__ Vr =
      v + ((size_t)(bg >> 3) * C_ + ((bg & 7) << 6) + d) * T_ + (part << 8);
  float s = 0.f;
  for (int t = 0; t < 256; t += 8) {
    const u16x8 x = *(const u16x8*)(Vr + t);
#pragma unroll
    for (int j = 0; j < 8; ++j) s += b2f(x[j]);
  }
  s += __shfl_down(s, 2, 64);
  s += __shfl_down(s, 1, 64);
  if (part == 0) vsum[(bg << 6) + d] = s;
}

// ---------------- S[h][q][t] = Q_h^T K_h (unscaled), K=64 ----------------
__global__ __launch_bounds__(256) void gemm_qk(const u16* __restrict__ qt,
                                               const u16* __restrict__ kt,
                                               float* __restrict__ S, int b) {
  const int h = blockIdx.z;
  const u16* __restrict__ Qb = qt + (size_t)b * (T_ * (size_t)C_) + (h << 6);
  const u16* __restrict__ Kb = kt + (size_t)b * (T_ * (size_t)C_) + (h << 6);
  float* __restrict__ Sh = S + (size_t)h * T_ * T_;
  const int m0 = blockIdx.y << 7;  // q
  const int n0 = blockIdx.x << 7;  // t
  __shared__ u16 As[128][72];
  __shared__ u16 Bs[128][72];
  const int tid = threadIdx.x;
  const int w = tid >> 6, lane = tid & 63, lr = lane & 15, lq = lane >> 4;
  const int mw = (w >> 1) << 6, nw = (w & 1) << 6;
#pragma unroll
  for (int it = 0; it < 4; ++it) {
    const int e = tid + (it << 8);
    const int r = e >> 3, c8 = e & 7;
    *(u16x8*)&As[r][c8 << 3] =
        *(const u16x8*)(Qb + (size_t)(m0 + r) * C_ + (c8 << 3));
    *(u16x8*)&Bs[r][c8 << 3] =
        *(const u16x8*)(Kb + (size_t)(n0 + r) * C_ + (c8 << 3));
  }
  __syncthreads();
  f32x4 acc[4][4] = {};
#pragma unroll
  for (int kk = 0; kk < 2; ++kk) {
    const int ko = (kk << 5) + (lq << 3);
    s16x8 a[4], bb[4];
#pragma unroll
    for (int i = 0; i < 4; ++i) a[i] = *(const s16x8*)&As[mw + (i << 4) + lr][ko];
#pragma unroll
    for (int j = 0; j < 4; ++j) bb[j] = *(const s16x8*)&Bs[nw + (j << 4) + lr][ko];
#pragma unroll
    for (int i = 0; i < 4; ++i)
#pragma unroll
      for (int j = 0; j < 4; ++j) acc[i][j] = mfma16(a[i], bb[j], acc[i][j]);
  }
#pragma unroll
  for (int i = 0; i < 4; ++i) {
    const int row = mw + (i << 4) + (lq << 2);
#pragma unroll
    for (int j = 0; j < 4; ++j) {
      const int col = nw + (j << 4) + lr;
#pragma unroll
      for (int r = 0; r < 4; ++r)
        Sh[(size_t)(m0 + row + r) * T_ + n0 + col] = acc[i][j][r];
    }
  }
}

// ---------------- per-q: mix heads, softmax, P bf16 (aliased), pssq ----------------
__global__ __launch_bounds__(256) void mix_softmax(float* __restrict__ S,
                                                   const float* __restrict__ wh,
                                                   float* __restrict__ pssq) {
  const int q = blockIdx.x;
  const int tid = threadIdx.x;
  const int lane = tid & 63, wid = tid >> 6;
  u16* __restrict__ P = (u16*)S;
  __shared__ float whs[64];
  __shared__ float redm[8][4], reds[8][4], redq[8][4];
  if (tid < 64) whs[tid] = wh[tid] * SCALE_;
  __syncthreads();
  f32x4 s[8];
#pragma unroll
  for (int h = 0; h < 8; ++h)
    s[h] = *(const f32x4*)(S + ((size_t)h * T_ + q) * T_ + (tid << 2));
  f32x4 v[8];
#pragma unroll
  for (int g = 0; g < 8; ++g) {
    f32x4 a = s[0] * whs[(g << 3) + 0];
#pragma unroll
    for (int h = 1; h < 8; ++h) a += s[h] * whs[(g << 3) + h];
    v[g] = a;
    float lm = fmaxf(fmaxf(a[0], a[1]), fmaxf(a[2], a[3]));
#pragma unroll
    for (int off = 32; off; off >>= 1) lm = fmaxf(lm, __shfl_xor(lm, off, 64));
    if (lane == 0) redm[g][wid] = lm;
  }
  __syncthreads();
#pragma unroll
  for (int g = 0; g < 8; ++g) {
    const float m =
        fmaxf(fmaxf(redm[g][0], redm[g][1]), fmaxf(redm[g][2], redm[g][3]));
    f32x4 e;
#pragma unroll
    for (int k = 0; k < 4; ++k) e[k] = __expf(v[g][k] - m);
    v[g] = e;
    float ls = e[0] + e[1] + e[2] + e[3];
#pragma unroll
    for (int off = 32; off; off >>= 1) ls += __shfl_xor(ls, off, 64);
    if (lane == 0) reds[g][wid] = ls;
  }
  __syncthreads();
#pragma unroll
  for (int g = 0; g < 8; ++g) {
    const float inv = 1.f / (reds[g][0] + reds[g][1] + reds[g][2] + reds[g][3]);
    const f32x4 p = v[g] * inv;
    u16x4 o;
#pragma unroll
    for (int k = 0; k < 4; ++k) o[k] = f2bf(p[k]);
    *(u16x4*)(P + ((size_t)((g << 10) + q)) * 2048 + (tid << 2)) = o;
    float lq2 = p[0] * p[0] + p[1] * p[1] + p[2] * p[2] + p[3] * p[3];
#pragma unroll
    for (int off = 32; off; off >>= 1) lq2 += __shfl_xor(lq2, off, 64);
    if (lane == 0) redq[g][wid] = lq2;
  }
  __syncthreads();
  if (tid < 8)
    pssq[(tid << 10) + q] = redq[tid][0] + redq[tid][1] + redq[tid][2] + redq[tid][3];
}

// ---------------- O = affine(P @ V^T) + beta'*vsum ----------------
__global__ __launch_bounds__(256) void gemm_pv(const u16* __restrict__ P,
                                               const u16* __restrict__ v,
                                               const float* __restrict__ pssq,
                                               const float* __restrict__ vsum,
                                               const float* __restrict__ gamma,
                                               const float* __restrict__ beta,
                                               u16* __restrict__ O, int b) {
  const int g = blockIdx.y;
  const int q0 = blockIdx.x << 6;
  const u16* __restrict__ Pg = P + (size_t)g * T_ * 2048;
  const u16* __restrict__ Vg = v + ((size_t)b * C_ + (g << 6)) * T_;
  u16* __restrict__ Og = O + (size_t)((b << 3) + g) * T_ * 64;
  __shared__ u16 Ps[64][40];
  __shared__ u16 Vs[64][40];
  __shared__ float ssq_red[4];
  __shared__ float aff[2];
  const int tid = threadIdx.x;
  const int w = tid >> 6, lane = tid & 63, lr = lane & 15, lq = lane >> 4;
  const int mw = (w >> 1) << 5, nw = (w & 1) << 5;
  // reduce pssq[g][0..1023]
  {
    const f32x4 pq = *(const f32x4*)(pssq + (g << 10) + (tid << 2));
    float ls = pq[0] + pq[1] + pq[2] + pq[3];
#pragma unroll
    for (int off = 32; off; off >>= 1) ls += __shfl_xor(ls, off, 64);
    if (lane == 0) ssq_red[w] = ls;
  }
  f32x4 acc[2][2] = {};
  const int r = tid >> 2, c4 = tid & 3;
  for (int k0 = 0; k0 < T_; k0 += 32) {
    __syncthreads();
    if (k0 == 0 && tid == 0) {
      const float ssq = ssq_red[0] + ssq_red[1] + ssq_red[2] + ssq_red[3];
      const float mean = 0.0009765625f;
      const float var = ssq * (1.f / 1048576.f) - mean * mean;
      const float istd = rsqrtf(var + EPS_);
      const float al = gamma[g] * istd;
      aff[0] = al;
      aff[1] = beta[g] - al * mean;
    }
    *(u16x8*)&Ps[r][c4 << 3] =
        *(const u16x8*)(Pg + (size_t)(q0 + r) * 2048 + k0 + (c4 << 3));
    *(u16x8*)&Vs[r][c4 << 3] =
        *(const u16x8*)(Vg + (size_t)r * T_ + k0 + (c4 << 3));
    __syncthreads();
    const int ko = lq << 3;
    s16x8 a[2], bb[2];
    a[0] = *(const s16x8*)&Ps[mw + lr][ko];
    a[1] = *(const s16x8*)&Ps[mw + 16 + lr][ko];
    bb[0] = *(const s16x8*)&Vs[nw + lr][ko];
    bb[1] = *(const s16x8*)&Vs[nw + 16 + lr][ko];
    acc[0][0] = mfma16(a[0], bb[0], acc[0][0]);
    acc[0][1] = mfma16(a[0], bb[1], acc[0][1]);
    acc[1][0] = mfma16(a[1], bb[0], acc[1][0]);
    acc[1][1] = mfma16(a[1], bb[1], acc[1][1]);
  }
  const float al = aff[0], bt = aff[1];
  const float* __restrict__ vsg = vsum + (((b << 3) + g) << 6);
#pragma unroll
  for (int i = 0; i < 2; ++i) {
    const int row = mw + (i << 4) + (lq << 2);
#pragma unroll
    for (int j = 0; j < 2; ++j) {
      const int col = nw + (j << 4) + lr;
      const float vs = vsg[col];
#pragma unroll
      for (int rr = 0; rr < 4; ++rr)
        Og[(size_t)(q0 + row + rr) * 64 + col] = f2bf(al * acc[i][j][rr] + bt * vs);
    }
  }
}

// ---------------- y = M @ Wp^T + bp,  M gathered from O ----------------
__global__ __launch_bounds__(256) void gemm_proj(const u16* __restrict__ O,
                                                 const float* __restrict__ wp,
                                                 const float* __restrict__ bp,
                                                 float* __restrict__ y) {
  const int b = blockIdx.z;
  const int m0 = blockIdx.y << 7;  // o
  const int n0 = blockIdx.x << 7;  // t
  const u16* __restrict__ Ob = O + (size_t)b * (8 * T_ * 64);
  __shared__ u16 As[128][40];
  __shared__ u16 Bs[128][40];
  const int tid = threadIdx.x;
  const int w = tid >> 6, lane = tid & 63, lr = lane & 15, lq = lane >> 4;
  const int mw = (w >> 1) << 6, nw = (w & 1) << 6;
  f32x4 acc[4][4] = {};
  for (int k0 = 0; k0 < C_; k0 += 32) {
#pragma unroll
    for (int it = 0; it < 2; ++it) {
      const int e = tid + (it << 8);
      const int r = e >> 2, c4 = e & 3;
      const float* wr = wp + (size_t)(m0 + r) * C_ + k0 + (c4 << 3);
      const float4 f0 = *(const float4*)wr;
      const float4 f1 = *(const float4*)(wr + 4);
      u16x8 o;
      o[0] = f2bf(f0.x); o[1] = f2bf(f0.y); o[2] = f2bf(f0.z); o[3] = f2bf(f0.w);
      o[4] = f2bf(f1.x); o[5] = f2bf(f1.y); o[6] = f2bf(f1.z); o[7] = f2bf(f1.w);
      *(u16x8*)&As[r][c4 << 3] = o;
      const int t = n0 + r;
      const int c = k0 + (c4 << 3);
      *(u16x8*)&Bs[r][c4 << 3] =
          *(const u16x8*)(Ob + (size_t)(t >> 7) * (T_ * 64) +
                          (size_t)(((t & 127) << 3) + (c >> 6)) * 64 + (c & 63));
    }
    __syncthreads();
    const int ko = lq << 3;
    s16x8 a[4], bb[4];
#pragma unroll
    for (int i = 0; i < 4; ++i) a[i] = *(const s16x8*)&As[mw + (i << 4) + lr][ko];
#pragma unroll
    for (int j = 0; j < 4; ++j) bb[j] = *(const s16x8*)&Bs[nw + (j << 4) + lr][ko];
#pragma unroll
    for (int i = 0; i < 4; ++i)
#pragma unroll
      for (int j = 0; j < 4; ++j) acc[i][j] = mfma16(a[i], bb[j], acc[i][j]);
    __syncthreads();
  }
#pragma unroll
  for (int i = 0; i < 4; ++i) {
    const int row = mw + (i << 4) + (lq << 2);
#pragma unroll
    for (int j = 0; j < 4; ++j) {
      const int col = nw + (j << 4) + lr;
#pragma unroll
      for (int r = 0; r < 4; ++r)
        y[(size_t)b * (C_ * (size_t)T_) + (size_t)(m0 + row + r) * T_ + n0 + col] =
            acc[i][j][r] + bp[m0 + row + r];
    }
  }
}

extern "C" void kernel_launch(void* const* d_in, const int* in_sizes, int n_in,
                              void* d_out, int out_size, void* d_ws,
                              size_t ws_size, hipStream_t stream) {
  const float* x = (const float*)d_in[0];
  const float* wq = (const float*)d_in[1];
  const float* wk = (const float*)d_in[2];
  const float* wv = (const float*)d_in[3];
  const float* wh = (const float*)d_in[4];
  const float* gm = (const float*)d_in[5];
  const float* bt = (const float*)d_in[6];
  const float* wp = (const float*)d_in[7];
  const float* bp = (const float*)d_in[8];
  float* y = (float*)d_out;
  char* wsb = (char*)d_ws;

  u16* Qt = (u16*)(wsb + QT_OFF);
  u16* Kt = (u16*)(wsb + KT_OFF);
  u16* V = (u16*)(wsb + V_OFF);
  u16* Xt = (u16*)(wsb + XT_OFF);
  float* Sf = (float*)(wsb + S_OFF);
  u16* Og = (u16*)(wsb + O_OFF);
  float* vsum = (float*)(wsb + VSUM_OFF);
  float* pssq = (float*)(wsb + PSSQ_OFF);

  transpose_x<<<dim3(16, 8, 4), 256, 0, stream>>>(x, Xt);
  gemm_qkt<<<dim3(8, 4, 8), 256, 0, stream>>>(Xt, wq, wk, Qt, Kt);
  gemm_v<<<dim3(8, 4, 4), 256, 0, stream>>>(Xt, wv, V);
  vsum_k<<<dim3(32), 256, 0, stream>>>(V, vsum);
  for (int b = 0; b < B_; ++b) {
    gemm_qk<<<dim3(8, 8, 8), 256, 0, stream>>>(Qt, Kt, Sf, b);
    mix_softmax<<<dim3(1024), 256, 0, stream>>>(Sf, wh, pssq);
    gemm_pv<<<dim3(16, 8), 256, 0, stream>>>((const u16*)Sf, V, pssq, vsum, gm,
                                             bt, Og, b);
  }
  gemm_proj<<<dim3(8, 4, 4), 256, 0, stream>>>(Og, wp, bp, y);
}